// Round 13
// baseline (54.395 us; speedup 1.0000x reference)
//
#include <hip/hip_runtime.h>
#include <cstdint>
#include <cstddef>

// Fused prefix-LM self-attention, B=8192, S=64, D=32, H=4, DH=8.
// Block = 128 thr = 2 waves = 1 batch; wave w owns heads {2w,2w+1}.
// bf16 MFMA 16x16x32 end-to-end. R12 math (sigma-permuted V^T so P feeds
// PV directly from registers; ones-row colsum; concat-head full-K tail).
// R13 = live-range diet to raise occupancy (unified VGPR+AGPR budget is
// the occupancy binder): i-tile (it) is the OUTER loop -- one transient
// oacc f32x4 instead of oacch[4], sqb built per-tile (4 dwords vs 16),
// O-frags collected in 8 dwords and stored to klds only after the
// head's ska reads complete (same aliasing-safety as R12). launch
// bounds relaxed to (128): no min-waves VGPR straitjacket (R6 lesson),
// no cap pressure either.
#define NB 8192

typedef __attribute__((ext_vector_type(8))) short short8;
typedef __attribute__((ext_vector_type(4))) float f32x4;

union S8U { short8 s; unsigned u[4]; uint4 v; };
union FI { float f; int i; unsigned u; };

static __device__ __forceinline__ unsigned pk2(float a, float b) {
    unsigned short ua = __builtin_bit_cast(unsigned short, (__bf16)a);
    unsigned short ub = __builtin_bit_cast(unsigned short, (__bf16)b);
    return (unsigned)ua | ((unsigned)ub << 16);
}

#define MFMA __builtin_amdgcn_mfma_f32_16x16x32_bf16
#define BPERM __builtin_amdgcn_ds_bpermute

__global__ __launch_bounds__(128) void fused_attn_mfma(
    const float* __restrict__ x,
    const int*   __restrict__ aatt,
    const float* __restrict__ Wq, const float* __restrict__ bq,
    const float* __restrict__ Wk, const float* __restrict__ bk,
    const float* __restrict__ Wv, const float* __restrict__ bv,
    const float* __restrict__ Wp, const float* __restrict__ bp,
    float* __restrict__ out)
{
    __shared__ __align__(16) short klds[64][40];   // K[seq][dim]; tail: O[i][dim]
    __shared__ __align__(16) short vbt[33][72];    // V^T[dim][sigma(j)] + ones row

    const int tid  = threadIdx.x;
    const int w    = tid >> 6;          // wave: heads {2w, 2w+1}, dims 16w..16w+15
    const int lane = tid & 63;
    const int q4   = lane >> 4;
    const int l15  = lane & 15;
    const int b    = blockIdx.x;

    const int aab = aatt[b];
    const unsigned bmask = (q4 == 0) ? 0xFFFFFFFFu : 0u;

    // allowed(j) == j <= max(i, aab-1); j = (compile-time C) + q4*4
    int cmpv[4];
#pragma unroll
    for (int it = 0; it < 4; ++it) cmpv[it] = max(l15 + 16*it, aab - 1) - q4*4;

    // ---- X fragments: row = tile*16+l15, k = q4*8+e ----
    short8 xa[4];
    const float* xb = x + (size_t)b * 64 * 32;
#pragma unroll
    for (int nt = 0; nt < 4; ++nt) {
        const float* p = xb + (nt*16 + l15)*32 + q4*8;
        float4 u0 = *(const float4*)p;
        float4 u1 = *(const float4*)(p + 4);
        S8U t;
        t.u[0] = pk2(u0.x, u0.y); t.u[1] = pk2(u0.z, u0.w);
        t.u[2] = pk2(u1.x, u1.y); t.u[3] = pk2(u1.z, u1.w);
        xa[nt] = t.s;
    }

    auto wrow = [&](const float* W, int row) -> short8 {
        const float* p = W + row*32 + q4*8;
        float4 u0 = *(const float4*)p;
        float4 u1 = *(const float4*)(p + 4);
        S8U t;
        t.u[0] = pk2(u0.x, u0.y); t.u[1] = pk2(u0.z, u0.w);
        t.u[2] = pk2(u1.x, u1.y); t.u[3] = pk2(u1.z, u1.w);
        return t.s;
    };

    const float escale = 0.35355339059327373f * 1.4426950408889634f; // 1/sqrt(8)*log2(e)

    // ---- Q^T (this wave's 16 dims) -> registers, bias+scale in f32 ----
    unsigned qpk01[4], qpk23[4];
    {
        short8 wa = wrow(Wq, 16*w + l15);
        float4 b4 = *(const float4*)(bq + 16*w + q4*4);
#pragma unroll
        for (int nt = 0; nt < 4; ++nt) {
            f32x4 acc = {0.f,0.f,0.f,0.f};
            acc = MFMA(wa, xa[nt], acc, 0,0,0);
            qpk01[nt] = pk2((acc[0]+b4.x)*escale, (acc[1]+b4.y)*escale);
            qpk23[nt] = pk2((acc[2]+b4.z)*escale, (acc[3]+b4.w)*escale);
        }
    }
    // ---- K^T (this wave's 16 dims) -> klds cols 16w.. ----
    {
        short8 wa = wrow(Wk, 16*w + l15);
        float4 b4 = *(const float4*)(bk + 16*w + q4*4);
#pragma unroll
        for (int nt = 0; nt < 4; ++nt) {
            f32x4 acc = {0.f,0.f,0.f,0.f};
            acc = MFMA(wa, xa[nt], acc, 0,0,0);
            uint2 w2;
            w2.x = pk2(acc[0]+b4.x, acc[1]+b4.y);
            w2.y = pk2(acc[2]+b4.z, acc[3]+b4.w);
            *(uint2*)&klds[nt*16 + l15][16*w + q4*4] = w2;
        }
    }
    // klds pad cols 32..39: zeroed (defensive)
    if (w == 1) {
        uint4 z4; z4.x = 0u; z4.y = 0u; z4.z = 0u; z4.w = 0u;
        *(uint4*)&klds[lane][32] = z4;
    }
    // ---- V (this wave's 16 dims) -> vbt rows 16w.. with sigma-permuted
    // columns: j = mt*16+q4*4+r  ->  p = (mt>>1)*32 + q4*8 + (mt&1)*4 + r ----
    {
        short8 wv = wrow(Wv, 16*w + l15);
        const float bvv = bv[16*w + l15];
#pragma unroll
        for (int mt = 0; mt < 4; ++mt) {
            f32x4 acc = {0.f,0.f,0.f,0.f};
            acc = MFMA(xa[mt], wv, acc, 0,0,0);
            uint2 w2;
            w2.x = pk2(acc[0]+bvv, acc[1]+bvv);
            w2.y = pk2(acc[2]+bvv, acc[3]+bvv);
            *(uint2*)&vbt[16*w + l15][(mt >> 1)*32 + q4*8 + (mt & 1)*4] = w2;
        }
    }
    // ones row 32 (all 64 positions; permutation-invariant)
    if (q4 == 0) {
        uint2 ones; ones.x = 0x3F803F80u; ones.y = 0x3F803F80u;
        *(uint2*)&vbt[32][l15*4] = ones;
    }

    // ---- head loop (2 heads per wave); it = OUTER loop, P in registers ----
#pragma unroll
    for (int hl = 0; hl < 2; ++hl) {
        const int idxA = (32*hl + l15) * 4;        // lane (q4=2hl,   l15)
        const int idxB = idxA + 64;                // lane (q4=2hl+1, l15)

        // V^T A-frag rows: dims for l15<8, ones row (colsum) for l15>=8
        const int avrow = (l15 < 8) ? (16*w + 8*hl + l15) : 32;
        S8U av0, av1;
        av0.v = *(const uint4*)&vbt[avrow][q4*8];
        av1.v = *(const uint4*)&vbt[avrow][32 + q4*8];

        unsigned opk01s[4], opk23s[4];

#pragma unroll
        for (int it = 0; it < 4; ++it) {
            // Q B-frag for this i-tile only (zero k>=8 via bmask)
            S8U sq;
            sq.u[0] = (unsigned)BPERM(idxA, (int)qpk01[it]) & bmask;
            sq.u[1] = (unsigned)BPERM(idxA, (int)qpk23[it]) & bmask;
            sq.u[2] = (unsigned)BPERM(idxB, (int)qpk01[it]) & bmask;
            sq.u[3] = (unsigned)BPERM(idxB, (int)qpk23[it]) & bmask;

            f32x4 oacc = {0.f,0.f,0.f,0.f};
#pragma unroll
            for (int jb = 0; jb < 2; ++jb) {
                S8U ska0, ska1;
                ska0.v = *(const uint4*)&klds[jb*32 + l15][16*w + 8*hl];
                ska1.v = *(const uint4*)&klds[jb*32 + 16 + l15][16*w + 8*hl];

                S8U pb;
                {   // jt = 0: P j-slots q4*4..+3 -> pb dwords 0,1
                    f32x4 sacc = {0.f,0.f,0.f,0.f};
                    sacc = MFMA(ska0.s, sq.s, sacc, 0,0,0);
                    float e[4];
#pragma unroll
                    for (int r = 0; r < 4; ++r) {
                        float ee = __builtin_amdgcn_exp2f(sacc[r]);
                        e[r] = (jb*32 + r <= cmpv[it]) ? ee : 0.0f;
                    }
                    pb.u[0] = pk2(e[0], e[1]); pb.u[1] = pk2(e[2], e[3]);
                }
                {   // jt = 1: P j-slots 16+q4*4..+3 -> pb dwords 2,3
                    f32x4 sacc = {0.f,0.f,0.f,0.f};
                    sacc = MFMA(ska1.s, sq.s, sacc, 0,0,0);
                    float e[4];
#pragma unroll
                    for (int r = 0; r < 4; ++r) {
                        float ee = __builtin_amdgcn_exp2f(sacc[r]);
                        e[r] = (jb*32 + 16 + r <= cmpv[it]) ? ee : 0.0f;
                    }
                    pb.u[2] = pk2(e[0], e[1]); pb.u[3] = pk2(e[2], e[3]);
                }
                oacc = MFMA(jb == 0 ? av0.s : av1.s, pb.s, oacc, 0,0,0);
            }

            // colsum in C-row 8 (lane 32+l15, reg 0) via the ones row
            FI s; s.i = BPERM((32 + l15) * 4, __builtin_bit_cast(int, oacc[0]));
            const float inv = __builtin_amdgcn_rcpf(s.f);
            opk01s[it] = pk2(oacc[0]*inv, oacc[1]*inv);
            opk23s[it] = pk2(oacc[2]*inv, oacc[3]*inv);
        }

        // deferred O-frag store: after ALL of this head's ska reads
        // (O-cols(hl) == ska-cols(hl); stores must follow reads)
#pragma unroll
        for (int it = 0; it < 4; ++it) {
            if (q4 < 2) {
                uint2 ow; ow.x = opk01s[it]; ow.y = opk23s[it];
                *(uint2*)&klds[it*16 + l15][(2*w + hl)*8 + q4*4] = ow;
            }
        }
    }

    // ---- tail: concat-head full-K out-projection ----
    __syncthreads();   // other wave's O-cols must be visible

    short8 wpb[2];
#pragma unroll
    for (int nt = 0; nt < 2; ++nt) wpb[nt] = wrow(Wp, nt*16 + l15);

    const float bpv[2] = { bp[l15], bp[16 + l15] };
    float* ob = out + (size_t)b * 64 * 32;
#pragma unroll
    for (int u = 0; u < 2; ++u) {           // this wave's i-tiles: 2w, 2w+1
        S8U oa; oa.v = *(const uint4*)&klds[(2*w + u)*16 + l15][q4*8];
#pragma unroll
        for (int nt = 0; nt < 2; ++nt) {
            f32x4 y = {0.f,0.f,0.f,0.f};
            y = MFMA(oa.s, wpb[nt], y, 0,0,0);
#pragma unroll
            for (int r = 0; r < 4; ++r)
                ob[((2*w + u)*16 + q4*4 + r)*32 + nt*16 + l15] = y[r] + bpv[nt];
        }
    }
}

extern "C" void kernel_launch(void* const* d_in, const int* in_sizes, int n_in,
                              void* d_out, int out_size, void* d_ws, size_t ws_size,
                              hipStream_t stream) {
    const float* x  = (const float*)d_in[0];
    const int*   aa = (const int*)d_in[1];
    const float* Wq = (const float*)d_in[2];
    const float* bq = (const float*)d_in[3];
    const float* Wk = (const float*)d_in[4];
    const float* bk = (const float*)d_in[5];
    const float* Wv = (const float*)d_in[6];
    const float* bv = (const float*)d_in[7];
    const float* Wp = (const float*)d_in[8];
    const float* bp = (const float*)d_in[9];
    float* out = (float*)d_out;

    dim3 grid(NB), block(128);
    hipLaunchKernelGGL(fused_attn_mfma, grid, block, 0, stream,
                       x, aa, Wq, bq, Wk, bk, Wv, bv, Wp, bp, out);
}

// Round 14
// 50.681 us; speedup vs baseline: 1.0733x; 1.0733x over previous
//
#include <hip/hip_runtime.h>
#include <cstdint>
#include <cstddef>

// Fused prefix-LM self-attention, B=8192, S=64, D=32, H=4, DH=8.
// Block = 128 thr = 2 waves = 1 batch; wave w owns heads {2w,2w+1}.
// bf16 MFMA 16x16x32 end-to-end. R12 math: sigma-permuted V^T so the
// P-fragments feed PV directly from registers (no P LDS round-trip);
// ones-row colsum; concat-head full-K tail projection (1 barrier).
// R14 = occupancy-class experiment: cross-round data (R7/R8/R12/R13)
// shows true reg allocation (unified VGPR+AGPR) sits in the (102,128]
// bucket -> 4 waves/SIMD regardless of source-level live-range diets.
// __launch_bounds__(128,5) caps alloc at ~102 to force the 5-waves/SIMD
// class (+25% latency hiding) at the cost of minor rematerialization.
// (Not R6's disaster: cap 102 vs need ~110, not cap 40 vs need 150.)
// Also: dead klds pad-zeroing deleted (ska reads span cols <=31 only).
#define NB 8192

typedef __attribute__((ext_vector_type(8))) short short8;
typedef __attribute__((ext_vector_type(4))) float f32x4;

union S8U { short8 s; unsigned u[4]; uint4 v; };
union FI { float f; int i; unsigned u; };

static __device__ __forceinline__ unsigned pk2(float a, float b) {
    unsigned short ua = __builtin_bit_cast(unsigned short, (__bf16)a);
    unsigned short ub = __builtin_bit_cast(unsigned short, (__bf16)b);
    return (unsigned)ua | ((unsigned)ub << 16);
}

#define MFMA __builtin_amdgcn_mfma_f32_16x16x32_bf16
#define BPERM __builtin_amdgcn_ds_bpermute

__global__ __launch_bounds__(128, 5) void fused_attn_mfma(
    const float* __restrict__ x,
    const int*   __restrict__ aatt,
    const float* __restrict__ Wq, const float* __restrict__ bq,
    const float* __restrict__ Wk, const float* __restrict__ bk,
    const float* __restrict__ Wv, const float* __restrict__ bv,
    const float* __restrict__ Wp, const float* __restrict__ bp,
    float* __restrict__ out)
{
    __shared__ __align__(16) short klds[64][40];   // K[seq][dim]; tail: O[i][dim]
    __shared__ __align__(16) short vbt[33][72];    // V^T[dim][sigma(j)] + ones row

    const int tid  = threadIdx.x;
    const int w    = tid >> 6;          // wave: heads {2w, 2w+1}, dims 16w..16w+15
    const int lane = tid & 63;
    const int q4   = lane >> 4;
    const int l15  = lane & 15;
    const int b    = blockIdx.x;

    const int aab = aatt[b];
    const unsigned bmask = (q4 == 0) ? 0xFFFFFFFFu : 0u;

    // allowed(j) == j <= max(i, aab-1); j = (compile-time C) + q4*4
    int cmpv[4];
#pragma unroll
    for (int it = 0; it < 4; ++it) cmpv[it] = max(l15 + 16*it, aab - 1) - q4*4;

    // ---- X fragments: row = tile*16+l15, k = q4*8+e ----
    short8 xa[4];
    const float* xb = x + (size_t)b * 64 * 32;
#pragma unroll
    for (int nt = 0; nt < 4; ++nt) {
        const float* p = xb + (nt*16 + l15)*32 + q4*8;
        float4 u0 = *(const float4*)p;
        float4 u1 = *(const float4*)(p + 4);
        S8U t;
        t.u[0] = pk2(u0.x, u0.y); t.u[1] = pk2(u0.z, u0.w);
        t.u[2] = pk2(u1.x, u1.y); t.u[3] = pk2(u1.z, u1.w);
        xa[nt] = t.s;
    }

    auto wrow = [&](const float* W, int row) -> short8 {
        const float* p = W + row*32 + q4*8;
        float4 u0 = *(const float4*)p;
        float4 u1 = *(const float4*)(p + 4);
        S8U t;
        t.u[0] = pk2(u0.x, u0.y); t.u[1] = pk2(u0.z, u0.w);
        t.u[2] = pk2(u1.x, u1.y); t.u[3] = pk2(u1.z, u1.w);
        return t.s;
    };

    const float escale = 0.35355339059327373f * 1.4426950408889634f; // 1/sqrt(8)*log2(e)

    // ---- Q^T (this wave's 16 dims) -> registers, bias+scale in f32 ----
    unsigned qpk01[4], qpk23[4];
    {
        short8 wa = wrow(Wq, 16*w + l15);
        float4 b4 = *(const float4*)(bq + 16*w + q4*4);
#pragma unroll
        for (int nt = 0; nt < 4; ++nt) {
            f32x4 acc = {0.f,0.f,0.f,0.f};
            acc = MFMA(wa, xa[nt], acc, 0,0,0);
            qpk01[nt] = pk2((acc[0]+b4.x)*escale, (acc[1]+b4.y)*escale);
            qpk23[nt] = pk2((acc[2]+b4.z)*escale, (acc[3]+b4.w)*escale);
        }
    }
    // ---- K^T (this wave's 16 dims) -> klds cols 16w.. ----
    {
        short8 wa = wrow(Wk, 16*w + l15);
        float4 b4 = *(const float4*)(bk + 16*w + q4*4);
#pragma unroll
        for (int nt = 0; nt < 4; ++nt) {
            f32x4 acc = {0.f,0.f,0.f,0.f};
            acc = MFMA(wa, xa[nt], acc, 0,0,0);
            uint2 w2;
            w2.x = pk2(acc[0]+b4.x, acc[1]+b4.y);
            w2.y = pk2(acc[2]+b4.z, acc[3]+b4.w);
            *(uint2*)&klds[nt*16 + l15][16*w + q4*4] = w2;
        }
    }
    // ---- V (this wave's 16 dims) -> vbt rows 16w.. with sigma-permuted
    // columns: j = mt*16+q4*4+r  ->  p = (mt>>1)*32 + q4*8 + (mt&1)*4 + r ----
    {
        short8 wv = wrow(Wv, 16*w + l15);
        const float bvv = bv[16*w + l15];
#pragma unroll
        for (int mt = 0; mt < 4; ++mt) {
            f32x4 acc = {0.f,0.f,0.f,0.f};
            acc = MFMA(xa[mt], wv, acc, 0,0,0);
            uint2 w2;
            w2.x = pk2(acc[0]+bvv, acc[1]+bvv);
            w2.y = pk2(acc[2]+bvv, acc[3]+bvv);
            *(uint2*)&vbt[16*w + l15][(mt >> 1)*32 + q4*8 + (mt & 1)*4] = w2;
        }
    }
    // ones row 32 (all 64 positions; permutation-invariant)
    if (q4 == 0) {
        uint2 ones; ones.x = 0x3F803F80u; ones.y = 0x3F803F80u;
        *(uint2*)&vbt[32][l15*4] = ones;
    }

    // ---- head loop (2 heads per wave); P stays in registers ----
#pragma unroll
    for (int hl = 0; hl < 2; ++hl) {
        const int idxA = (32*hl + l15) * 4;        // lane (q4=2hl,   l15)
        const int idxB = idxA + 64;                // lane (q4=2hl+1, l15)

        // Q B-frags: zero k>=8 via bmask
        short8 sqb[4];
#pragma unroll
        for (int it = 0; it < 4; ++it) {
            S8U t;
            t.u[0] = (unsigned)BPERM(idxA, (int)qpk01[it]) & bmask;
            t.u[1] = (unsigned)BPERM(idxA, (int)qpk23[it]) & bmask;
            t.u[2] = (unsigned)BPERM(idxB, (int)qpk01[it]) & bmask;
            t.u[3] = (unsigned)BPERM(idxB, (int)qpk23[it]) & bmask;
            sqb[it] = t.s;
        }

        // V^T A-frag rows: dims for l15<8, ones row (colsum) for l15>=8
        const int avrow = (l15 < 8) ? (16*w + 8*hl + l15) : 32;

        f32x4 oacch[4];
#pragma unroll
        for (int it = 0; it < 4; ++it) oacch[it] = (f32x4){0.f,0.f,0.f,0.f};

#pragma unroll
        for (int jb = 0; jb < 2; ++jb) {
            S8U ska0, ska1, av;
            ska0.v = *(const uint4*)&klds[jb*32 + l15][16*w + 8*hl];
            ska1.v = *(const uint4*)&klds[jb*32 + 16 + l15][16*w + 8*hl];
            av.v   = *(const uint4*)&vbt[avrow][jb*32 + q4*8];

#pragma unroll
            for (int it = 0; it < 4; ++it) {
                S8U pb;
                {   // jt = 0: P j-slots q4*4..+3 -> pb dwords 0,1
                    f32x4 sacc = {0.f,0.f,0.f,0.f};
                    sacc = MFMA(ska0.s, sqb[it], sacc, 0,0,0);
                    float e[4];
#pragma unroll
                    for (int r = 0; r < 4; ++r) {
                        float ee = __builtin_amdgcn_exp2f(sacc[r]);
                        e[r] = (jb*32 + r <= cmpv[it]) ? ee : 0.0f;
                    }
                    pb.u[0] = pk2(e[0], e[1]); pb.u[1] = pk2(e[2], e[3]);
                }
                {   // jt = 1: P j-slots 16+q4*4..+3 -> pb dwords 2,3
                    f32x4 sacc = {0.f,0.f,0.f,0.f};
                    sacc = MFMA(ska1.s, sqb[it], sacc, 0,0,0);
                    float e[4];
#pragma unroll
                    for (int r = 0; r < 4; ++r) {
                        float ee = __builtin_amdgcn_exp2f(sacc[r]);
                        e[r] = (jb*32 + 16 + r <= cmpv[it]) ? ee : 0.0f;
                    }
                    pb.u[2] = pk2(e[0], e[1]); pb.u[3] = pk2(e[2], e[3]);
                }
                oacch[it] = MFMA(av.s, pb.s, oacch[it], 0,0,0);
            }
        }

        // colsum arrived in C-row 8 (lane 32+l15, reg 0) via the ones row;
        // normalize and store O-frags to own klds cols immediately
#pragma unroll
        for (int it = 0; it < 4; ++it) {
            FI s; s.i = BPERM((32 + l15) * 4, __builtin_bit_cast(int, oacch[it][0]));
            const float inv = __builtin_amdgcn_rcpf(s.f);
            const unsigned o01 = pk2(oacch[it][0]*inv, oacch[it][1]*inv);
            const unsigned o23 = pk2(oacch[it][2]*inv, oacch[it][3]*inv);
            if (q4 < 2) {
                uint2 ow; ow.x = o01; ow.y = o23;
                *(uint2*)&klds[it*16 + l15][(2*w + hl)*8 + q4*4] = ow;
            }
        }
    }

    // ---- tail: concat-head full-K out-projection ----
    __syncthreads();   // other wave's O-cols must be visible

    short8 wpb[2];
#pragma unroll
    for (int nt = 0; nt < 2; ++nt) wpb[nt] = wrow(Wp, nt*16 + l15);

    const float bpv[2] = { bp[l15], bp[16 + l15] };
    float* ob = out + (size_t)b * 64 * 32;
#pragma unroll
    for (int u = 0; u < 2; ++u) {           // this wave's i-tiles: 2w, 2w+1
        S8U oa; oa.v = *(const uint4*)&klds[(2*w + u)*16 + l15][q4*8];
#pragma unroll
        for (int nt = 0; nt < 2; ++nt) {
            f32x4 y = {0.f,0.f,0.f,0.f};
            y = MFMA(oa.s, wpb[nt], y, 0,0,0);
#pragma unroll
            for (int r = 0; r < 4; ++r)
                ob[((2*w + u)*16 + q4*4 + r)*32 + nt*16 + l15] = y[r] + bpv[nt];
        }
    }
}

extern "C" void kernel_launch(void* const* d_in, const int* in_sizes, int n_in,
                              void* d_out, int out_size, void* d_ws, size_t ws_size,
                              hipStream_t stream) {
    const float* x  = (const float*)d_in[0];
    const int*   aa = (const int*)d_in[1];
    const float* Wq = (const float*)d_in[2];
    const float* bq = (const float*)d_in[3];
    const float* Wk = (const float*)d_in[4];
    const float* bk = (const float*)d_in[5];
    const float* Wv = (const float*)d_in[6];
    const float* bv = (const float*)d_in[7];
    const float* Wp = (const float*)d_in[8];
    const float* bp = (const float*)d_in[9];
    float* out = (float*)d_out;

    dim3 grid(NB), block(128);
    hipLaunchKernelGGL(fused_attn_mfma, grid, block, 0, stream,
                       x, aa, Wq, bq, Wk, bk, Wv, bv, Wp, bp, out);
}